// Round 3
// baseline (1042.944 us; speedup 1.0000x reference)
//
#include <hip/hip_runtime.h>
#include <stdint.h>

typedef __bf16 bf16_t;
typedef __bf16 bf16x8 __attribute__((ext_vector_type(8)));
typedef float  f32x4  __attribute__((ext_vector_type(4)));

__device__ __forceinline__ void gl_lds16(const void* g, void* lds) {
  __builtin_amdgcn_global_load_lds(
      (const __attribute__((address_space(1))) uint32_t*)g,
      (__attribute__((address_space(3))) uint32_t*)lds, 16, 0, 0);
}

// C[m][n] = (sum_k A[m][k] * BT[n][k]) * scale + bias[n] (+ res[m][n])
// A: M x K bf16 (lda), BT: N x K bf16 (ldb). 128x128 tile, BK=32,
// 256 thr = 4 waves (2x2), each wave 64x64 = 4x4 of mfma_f32_16x16x32_bf16.
// Batched over blockIdx.z with element strides sA/sB/sC.
template<bool OUT_BF16, bool HAS_BIAS, bool HAS_RES>
__global__ __launch_bounds__(256)
void gemm_bt(const bf16_t* __restrict__ A, int64_t lda, int64_t sA,
             const bf16_t* __restrict__ BT, int64_t ldb, int64_t sB,
             void* __restrict__ Cv, int64_t ldc, int64_t sC,
             const float* __restrict__ bias, const float* __restrict__ res,
             float scale, int K)
{
  __shared__ __align__(16) bf16_t lA[128 * 32];
  __shared__ __align__(16) bf16_t lB[128 * 32];
  const int t = threadIdx.x;
  const int z = blockIdx.z;

  // T1: XCD swizzle (8 XCDs); only applied when bijective (nwg % 8 == 0 —
  // true for every launch in this file).
  const int gx  = gridDim.x;
  const int nwg = gx * gridDim.y;
  int flat = blockIdx.y * gx + blockIdx.x;
  if ((nwg & 7) == 0) flat = (flat & 7) * (nwg >> 3) + (flat >> 3);
  const int tn = flat % gx;          // tile col
  const int tm = flat / gx;          // tile row

  const bf16_t* Ab = A + (int64_t)z * sA;
  const bf16_t* Bb = BT + (int64_t)z * sB;
  const int64_t bm = (int64_t)tm * 128;
  const int64_t bn = (int64_t)tn * 128;
  const int l   = t & 63;
  const int wid = t >> 6;
  const int wm  = (wid >> 1) * 64;   // wave row offset in tile
  const int wn  = (wid & 1) * 64;    // wave col offset in tile
  const int lr  = l & 15;            // fragment row (A) / col (B) / col (C)
  const int kg  = l >> 4;            // k-group: k = kg*8 + j
  const int srow = t >> 2;           // staging row (0..63, +64 on pass 1)
  const int scol = (t & 3) * 8;      // staging k-offset (elements)
  char* lAc = (char*)lA;
  char* lBc = (char*)lB;
  const int wbase = (t & 192) * 16;  // wave-uniform LDS byte base

  f32x4 acc[4][4] = {};

  for (int k0 = 0; k0 < K; k0 += 32) {
    const bf16_t* ga = Ab + (bm + srow) * lda + k0 + scol;
    const bf16_t* gb = Bb + (bn + srow) * ldb + k0 + scol;
    gl_lds16(ga,            lAc + wbase);
    gl_lds16(ga + 64 * lda, lAc + 4096 + wbase);
    gl_lds16(gb,            lBc + wbase);
    gl_lds16(gb + 64 * ldb, lBc + 4096 + wbase);
    __syncthreads();
    bf16x8 af[4], bfv[4];
#pragma unroll
    for (int m = 0; m < 4; ++m)
      af[m] = *(const bf16x8*)(lA + (wm + m * 16 + lr) * 32 + kg * 8);
#pragma unroll
    for (int n = 0; n < 4; ++n)
      bfv[n] = *(const bf16x8*)(lB + (wn + n * 16 + lr) * 32 + kg * 8);
#pragma unroll
    for (int m = 0; m < 4; ++m)
#pragma unroll
      for (int n = 0; n < 4; ++n)
        acc[m][n] = __builtin_amdgcn_mfma_f32_16x16x32_bf16(af[m], bfv[n], acc[m][n], 0, 0, 0);
    __syncthreads();
  }

  bf16_t* C16 = (bf16_t*)Cv + (int64_t)z * sC;
  float*  C32 = (float*)Cv + (int64_t)z * sC;
#pragma unroll
  for (int m = 0; m < 4; ++m) {
#pragma unroll
    for (int n = 0; n < 4; ++n) {
      const int64_t col = bn + wn + n * 16 + lr;
      const float bv = HAS_BIAS ? bias[col] : 0.0f;
#pragma unroll
      for (int r = 0; r < 4; ++r) {
        const int64_t row = bm + wm + m * 16 + kg * 4 + r;  // C/D: col=l&15, row=(l>>4)*4+r
        float v = acc[m][n][r] * scale + bv;
        if constexpr (HAS_RES) v += res[row * ldc + col];
        if constexpr (OUT_BF16) C16[row * ldc + col] = (bf16_t)v;
        else                    C32[row * ldc + col] = v;
      }
    }
  }
}

// out[c][r] = bf16(in[r][c]); grid (cols/32, rows/32[,batch]), block 256 flat.
template<typename TIN>
__device__ __forceinline__
void transpose_body(const TIN* __restrict__ in, int64_t ldi,
                    bf16_t* __restrict__ out, int64_t ldo)
{
  __shared__ float tile[32][33];
  const int bx = blockIdx.x * 32;
  const int by = blockIdx.y * 32;
  const int tx = threadIdx.x & 31;
  const int ty = threadIdx.x >> 5;  // 0..7
#pragma unroll
  for (int i = 0; i < 32; i += 8)
    tile[ty + i][tx] = (float)in[(int64_t)(by + ty + i) * ldi + bx + tx];
  __syncthreads();
#pragma unroll
  for (int i = 0; i < 32; i += 8)
    out[(int64_t)(bx + ty + i) * ldo + by + tx] = (bf16_t)tile[tx][ty + i];
}

template<typename TIN>
__global__ __launch_bounds__(256)
void transpose_to_bf16(const TIN* __restrict__ in, int64_t ldi,
                       bf16_t* __restrict__ out, int64_t ldo)
{
  transpose_body<TIN>(in, ldi, out, ldo);
}

struct Ptr10 { const float* p[10]; };

// All 10 weight transposes in one dispatch: grid (64, 64, 10).
__global__ __launch_bounds__(256)
void weight_prep(Ptr10 ws, bf16_t* __restrict__ out, int64_t stride)
{
  transpose_body<float>(ws.p[blockIdx.z], 2048, out + (int64_t)blockIdx.z * stride, 2048);
}

__global__ __launch_bounds__(256)
void f32_to_bf16_k(const float* __restrict__ in, bf16_t* __restrict__ out)
{
  const int64_t i = ((int64_t)blockIdx.x * 256 + threadIdx.x) * 8;
  const float4 a = *(const float4*)(in + i);
  const float4 b = *(const float4*)(in + i + 4);
  bf16x8 o;
  o[0] = (bf16_t)a.x; o[1] = (bf16_t)a.y; o[2] = (bf16_t)a.z; o[3] = (bf16_t)a.w;
  o[4] = (bf16_t)b.x; o[5] = (bf16_t)b.y; o[6] = (bf16_t)b.z; o[7] = (bf16_t)b.w;
  *(bf16x8*)(out + i) = o;
}

// In-place row softmax over 2048 bf16; one block (256 thr) per row.
__global__ __launch_bounds__(256)
void softmax_rows(bf16_t* __restrict__ P)
{
  const int64_t row = blockIdx.x;
  bf16_t* p = P + row * 2048;
  const int t = threadIdx.x;
  bf16x8 v = *(bf16x8*)(p + t * 8);
  float x[8];
#pragma unroll
  for (int j = 0; j < 8; ++j) x[j] = (float)v[j];
  float m = -1e30f;
#pragma unroll
  for (int j = 0; j < 8; ++j) m = fmaxf(m, x[j]);
#pragma unroll
  for (int off = 32; off; off >>= 1) m = fmaxf(m, __shfl_xor(m, off));
  __shared__ float rm[4], rs[4];
  const int l = t & 63, w = t >> 6;
  if (l == 0) rm[w] = m;
  __syncthreads();
  m = fmaxf(fmaxf(rm[0], rm[1]), fmaxf(rm[2], rm[3]));
  float s = 0.f;
#pragma unroll
  for (int j = 0; j < 8; ++j) { x[j] = __expf(x[j] - m); s += x[j]; }
#pragma unroll
  for (int off = 32; off; off >>= 1) s += __shfl_xor(s, off);
  if (l == 0) rs[w] = s;
  __syncthreads();
  s = rs[0] + rs[1] + rs[2] + rs[3];
  const float inv = 1.0f / s;
  bf16x8 o;
#pragma unroll
  for (int j = 0; j < 8; ++j) o[j] = (bf16_t)(x[j] * inv);
  *(bf16x8*)(p + t * 8) = o;
}

// LN(y)*g + b -> xout (fp32) and xb (bf16). One block per row.
// (residual already folded into y by the producing GEMM's epilogue)
__global__ __launch_bounds__(256)
void add_ln(const float* __restrict__ y,
            const float* __restrict__ g, const float* __restrict__ b,
            float* __restrict__ xout, bf16_t* __restrict__ xb)
{
  const int64_t row = blockIdx.x;
  const int t = threadIdx.x;
  const int64_t base = row * 2048 + t * 8;
  const float4 y0 = *(const float4*)(y + base);
  const float4 y1 = *(const float4*)(y + base + 4);
  float x[8] = {y0.x, y0.y, y0.z, y0.w, y1.x, y1.y, y1.z, y1.w};
  float s = 0.f, q = 0.f;
#pragma unroll
  for (int j = 0; j < 8; ++j) { s += x[j]; q += x[j] * x[j]; }
#pragma unroll
  for (int off = 32; off; off >>= 1) { s += __shfl_xor(s, off); q += __shfl_xor(q, off); }
  __shared__ float rs[4], rq[4];
  const int l = t & 63, w = t >> 6;
  if (l == 0) { rs[w] = s; rq[w] = q; }
  __syncthreads();
  s = rs[0] + rs[1] + rs[2] + rs[3];
  q = rq[0] + rq[1] + rq[2] + rq[3];
  const float mean = s * (1.f / 2048.f);
  const float var  = q * (1.f / 2048.f) - mean * mean;
  const float inv  = rsqrtf(var + 1e-5f);
  const float4 g0 = *(const float4*)(g + t * 8);
  const float4 g1 = *(const float4*)(g + t * 8 + 4);
  const float4 b0 = *(const float4*)(b + t * 8);
  const float4 b1 = *(const float4*)(b + t * 8 + 4);
  float o[8];
  o[0] = (x[0] - mean) * inv * g0.x + b0.x; o[1] = (x[1] - mean) * inv * g0.y + b0.y;
  o[2] = (x[2] - mean) * inv * g0.z + b0.z; o[3] = (x[3] - mean) * inv * g0.w + b0.w;
  o[4] = (x[4] - mean) * inv * g1.x + b1.x; o[5] = (x[5] - mean) * inv * g1.y + b1.y;
  o[6] = (x[6] - mean) * inv * g1.z + b1.z; o[7] = (x[7] - mean) * inv * g1.w + b1.w;
  *(float4*)(xout + base)     = make_float4(o[0], o[1], o[2], o[3]);
  *(float4*)(xout + base + 4) = make_float4(o[4], o[5], o[6], o[7]);
  bf16x8 ob;
#pragma unroll
  for (int j = 0; j < 8; ++j) ob[j] = (bf16_t)o[j];
  *(bf16x8*)(xb + base) = ob;
}

extern "C" void kernel_launch(void* const* d_in, const int* in_sizes, int n_in,
                              void* d_out, int out_size, void* d_ws, size_t ws_size,
                              hipStream_t stream)
{
  constexpr int S = 2048, D = 2048, H = 16, dk = 128;
  constexpr int64_t DD = (int64_t)D * D;
  constexpr int64_t SS = (int64_t)S * S;

  const float* X    = (const float*)d_in[0];
  const float* wq1  = (const float*)d_in[1];
  const float* wk1  = (const float*)d_in[2];
  const float* wv1  = (const float*)d_in[3];
  const float* wfc1 = (const float*)d_in[4];
  const float* bfc1 = (const float*)d_in[5];
  const float* g1   = (const float*)d_in[6];
  const float* b1   = (const float*)d_in[7];
  const float* wl1  = (const float*)d_in[8];
  const float* bl1  = (const float*)d_in[9];
  const float* g2   = (const float*)d_in[10];
  const float* b2   = (const float*)d_in[11];
  const float* wq2  = (const float*)d_in[12];
  const float* wk2  = (const float*)d_in[13];
  const float* wv2  = (const float*)d_in[14];
  const float* wfc2 = (const float*)d_in[15];
  const float* bfc2 = (const float*)d_in[16];
  const float* g3   = (const float*)d_in[17];
  const float* b3   = (const float*)d_in[18];
  const float* wl2  = (const float*)d_in[19];
  const float* bl2  = (const float*)d_in[20];
  const float* g4   = (const float*)d_in[21];
  const float* b4   = (const float*)d_in[22];

  // workspace layout
  char* p = (char*)d_ws;
  bf16_t* WT  = (bf16_t*)p; p += 10 * DD * 2;            // 10 transposed bf16 weights
  bf16_t* Xb  = (bf16_t*)p; p += DD * 2;                 // current X in bf16
  bf16_t* QKV = (bf16_t*)p; p += (int64_t)S * 3 * D * 2; // fused QKV output, S x 6144
  bf16_t* VT  = (bf16_t*)p; p += DD * 2;                 // V^T (D x S), per-head V_h^T stacked
  bf16_t* CTXT= (bf16_t*)p; p += DD * 2;                 // ctx^T == scrambled-reshape matrix
  float*  OUTF= (float*)p;  p += DD * 4;                 // GEMM fp32 output (incl. residual)
  float*  XF  = (float*)p;  p += DD * 4;                 // current X fp32
  bf16_t* P   = (bf16_t*)p;                              // attention probs, CH heads
  const size_t fixed = (size_t)(p - (char*)d_ws);
  int CH = 16;                                            // heads per chunk
  while (CH > 1 && fixed + (size_t)CH * SS * 2 > ws_size) CH >>= 1;

  const dim3 TB(256);

  auto gemm = [&](const bf16_t* A, int64_t lda, int64_t sA,
                  const bf16_t* BT, int64_t ldb, int64_t sB,
                  void* C, int64_t ldc, int64_t sC,
                  const float* bias, const float* res, float scale,
                  int M, int N, int K, int batch, bool obf) {
    dim3 gg(N / 128, M / 128, batch);
    if (obf) {
      if (bias) gemm_bt<true, true , false><<<gg, TB, 0, stream>>>(A, lda, sA, BT, ldb, sB, C, ldc, sC, bias, res, scale, K);
      else      gemm_bt<true, false, false><<<gg, TB, 0, stream>>>(A, lda, sA, BT, ldb, sB, C, ldc, sC, bias, res, scale, K);
    } else {
      // fp32-out path is always bias + residual here
      gemm_bt<false, true, true><<<gg, TB, 0, stream>>>(A, lda, sA, BT, ldb, sB, C, ldc, sC, bias, res, scale, K);
    }
  };

  // one-time: weights -> bf16, transposed to N x K; q,k,v contiguous per layer
  Ptr10 wsrc = {{wq1, wk1, wv1, wfc1, wl1, wq2, wk2, wv2, wfc2, wl2}};
  weight_prep<<<dim3(64, 64, 10), TB, 0, stream>>>(wsrc, WT, DD);
  f32_to_bf16_k<<<dim3(DD / 2048), TB, 0, stream>>>(X, Xb);

  const float scl = 0.08838834764831845f;  // 1/sqrt(128)

  auto layer = [&](const float* resX, int sq, int sfc, int sfl,
                   const float* bfc, const float* ga, const float* ba,
                   const float* bl, const float* gb, const float* bb,
                   float* ln2_out) {
    // QKV projection: (S x 3D) bf16, weight slots sq..sq+2 contiguous
    gemm(Xb, D, 0, WT + (int64_t)sq * DD, D, 0, QKV, 3 * D, 0,
         nullptr, nullptr, 1.f, S, 3 * D, D, 1, true);
    // V^T (per-head V_h^T stacked: rows h*dk..h*dk+127)
    transpose_to_bf16<bf16_t><<<dim3(64, 64), TB, 0, stream>>>(QKV + 2 * D, 3 * D, VT, S);
    // attention, CH heads at a time
    for (int hb = 0; hb < H; hb += CH) {
      gemm(QKV + (int64_t)hb * dk, 3 * D, dk,             // Q_h  (lda 6144, head stride 128)
           QKV + D + (int64_t)hb * dk, 3 * D, dk,         // K_h  as BT (N x K) directly
           P, S, SS, nullptr, nullptr, scl, S, S, dk, CH, true);
      softmax_rows<<<dim3(CH * S), TB, 0, stream>>>(P);
      // PV-transposed: R_h = V_h^T · P_h^T  -> writes CTXT rows h*dk.. directly
      gemm(VT + (int64_t)hb * dk * S, S, (int64_t)dk * S, // A = V_h^T (128 x S)
           P, S, SS,                                      // BT = P_h (S x S)
           CTXT + (int64_t)hb * dk * S, S, (int64_t)dk * S,
           nullptr, nullptr, 1.f, dk, S, S, CH, true);
    }
    // fc on the scrambled-reshape matrix (= CTXT), residual fused
    gemm(CTXT, S, 0, WT + (int64_t)sfc * DD, D, 0, OUTF, D, 0,
         bfc, resX, 1.f, D, D, S, 1, false);
    add_ln<<<dim3(S), TB, 0, stream>>>(OUTF, ga, ba, XF, Xb);
    // FFN linear, residual (= post-LN1 x) fused
    gemm(Xb, D, 0, WT + (int64_t)sfl * DD, D, 0, OUTF, D, 0,
         bl, XF, 1.f, S, D, D, 1, false);
    add_ln<<<dim3(S), TB, 0, stream>>>(OUTF, gb, bb, ln2_out, Xb);
  };

  layer(X,  0, 3, 4, bfc1, g1, b1, bl1, g2, b2, XF);
  layer(XF, 5, 8, 9, bfc2, g3, b3, bl2, g4, b4, (float*)d_out);
}